// Round 1
// baseline (720.773 us; speedup 1.0000x reference)
//
#include <hip/hip_runtime.h>
#include <math.h>

#define LRES 1024
#define TOPK 48
#define EPB  16
#define NEDGE (LRES*TOPK)

// ---- output layout (floats). Tuple concat: E, E_idx, E_s, E_idx_sub ----
#define OUT_E     0
#define OUT_EIDX  6291456          // 1024*48*128
#define OUT_ES    6340608          // + 49152
#define OUT_EIDX2 12632064         // + 6291456

// ---- workspace layout (float offsets) ----
#define WS_COORDS 0                // 1024*15
#define WS_WE4    15360            // 416*128  quad-packed transposed W_e
#define WS_WS4    68608            // 1280*128 quad-packed transposed W_s
#define WS_DNB    232448           // 49152
#define WS_EIDX   281600           // 49152 (ints)

// pair -> anchor index maps (N=0, Ca=1, C=2, O=3, Cb=4)
__constant__ int PA[24] = {0,2,3,4,1,1,1,1,0,0,0,4,4,3,0,2,3,4,2,3,4,2,3,2};
__constant__ int PB[24] = {0,2,3,4,0,2,3,4,2,3,4,2,3,2,1,1,1,1,0,0,0,4,4,3};

// ---------------- K1: per-residue coords N,Ca,C,O,Cb ----------------
__global__ void k_coords(const float* __restrict__ X, float* __restrict__ coords) {
    int r = blockIdx.x * blockDim.x + threadIdx.x;
    if (r >= LRES) return;
    const float* xr = X + r * 37 * 3;
    float N[3], Ca[3], C[3], O[3], bv[3], cv[3], av[3];
    #pragma unroll
    for (int d = 0; d < 3; ++d) {
        N[d]  = xr[0*3 + d];
        Ca[d] = xr[1*3 + d];
        C[d]  = xr[2*3 + d];
        O[d]  = xr[4*3 + d];
        bv[d] = Ca[d] - N[d];
        cv[d] = C[d] - Ca[d];
    }
    av[0] = bv[1]*cv[2] - bv[2]*cv[1];
    av[1] = bv[2]*cv[0] - bv[0]*cv[2];
    av[2] = bv[0]*cv[1] - bv[1]*cv[0];
    float* o = coords + r * 15;
    #pragma unroll
    for (int d = 0; d < 3; ++d) {
        float Cb = -0.58273431f*av[d] + 0.56802827f*bv[d] - 0.54067466f*cv[d] + Ca[d];
        o[0*3 + d] = N[d];
        o[1*3 + d] = Ca[d];
        o[2*3 + d] = C[d];
        o[3*3 + d] = O[d];
        o[4*3 + d] = Cb;
    }
}

// ---------------- K2: transpose + quad-pack weights ----------------
// We4[(c4*128+f)*4+q] = We[f*416 + 4*c4+q];  Ws4 likewise with 1280 cols.
__global__ void k_transpose(const float* __restrict__ We, const float* __restrict__ Ws,
                            float* __restrict__ We4, float* __restrict__ Ws4) {
    int t = blockIdx.x * 256 + threadIdx.x;
    if (t < 416*128) {
        int q = t & 3, f = (t >> 2) & 127, c4 = t >> 9;
        We4[t] = We[f*416 + c4*4 + q];
    }
    if (t < 1280*128) {
        int q = t & 3, f = (t >> 2) & 127, c4 = t >> 9;
        Ws4[t] = Ws[f*1280 + c4*4 + q];
    }
}

// ---------------- K3: distance row + top-48 (ascending, tie->low idx) ----------------
__global__ __launch_bounds__(256) void k_topk(const float* __restrict__ coords,
                                              const float* __restrict__ mask,
                                              float* __restrict__ Dnb,
                                              int* __restrict__ Eidx,
                                              float* __restrict__ out) {
    __shared__ float sD[LRES];
    __shared__ float wv[4]; __shared__ int wi[4];
    __shared__ float sMax[4];
    int i = blockIdx.x, t = threadIdx.x;
    float cx = coords[i*15+3], cy = coords[i*15+4], cz = coords[i*15+5];
    float mi = mask[i];
    float lmax = -1e30f;
    for (int j = t; j < LRES; j += 256) {
        float dx = cx - coords[j*15+3];
        float dy = cy - coords[j*15+4];
        float dz = cz - coords[j*15+5];
        float d  = sqrtf(dx*dx + dy*dy + dz*dz + 1e-6f);
        float dm = mi * mask[j] * d;
        sD[j] = dm;
        lmax = fmaxf(lmax, dm);
    }
    for (int off = 32; off; off >>= 1) lmax = fmaxf(lmax, __shfl_down(lmax, off));
    if ((t & 63) == 0) sMax[t >> 6] = lmax;
    __syncthreads();
    float dmax = fmaxf(fmaxf(sMax[0], sMax[1]), fmaxf(sMax[2], sMax[3]));
    for (int j = t; j < LRES; j += 256) {
        float m2 = mi * mask[j];
        sD[j] += (1.0f - m2) * dmax;
    }
    __syncthreads();
    for (int it = 0; it < TOPK; ++it) {
        float bv = 3e38f; int bi = LRES;
        for (int j = t; j < LRES; j += 256) {
            float v = sD[j];
            if (v < bv) { bv = v; bi = j; }
        }
        for (int off = 32; off; off >>= 1) {
            float ov = __shfl_down(bv, off);
            int   oi = __shfl_down(bi, off);
            if (ov < bv || (ov == bv && oi < bi)) { bv = ov; bi = oi; }
        }
        if ((t & 63) == 0) { wv[t >> 6] = bv; wi[t >> 6] = bi; }
        __syncthreads();
        if (t == 0) {
            for (int w = 1; w < 4; ++w)
                if (wv[w] < bv || (wv[w] == bv && wi[w] < bi)) { bv = wv[w]; bi = wi[w]; }
            sD[bi] = 3e38f;
            int id = i*TOPK + it;
            Dnb[id]  = bv;
            Eidx[id] = bi;
            out[OUT_EIDX  + id] = (float)bi;
            out[OUT_EIDX2 + id] = (float)bi;
        }
        __syncthreads();
    }
}

// ---------------- K4: edge features E (416 -> 128 matvec + LN) ----------------
__global__ __launch_bounds__(128) void k_edgeE(const float* __restrict__ coords,
                                               const float* __restrict__ We4,
                                               const float* __restrict__ Dnb,
                                               const int* __restrict__ Eidx,
                                               const int* __restrict__ ri,
                                               const int* __restrict__ ch,
                                               const float* __restrict__ Wpos,
                                               const float* __restrict__ bpos,
                                               const float* __restrict__ ge,
                                               const float* __restrict__ be,
                                               float* __restrict__ out) {
    __shared__ float feat[EPB*416];      // reused as hbuf (EPB*128) after matvec
    __shared__ float sdist[EPB*25];
    __shared__ float sA[EPB*15], sB[EPB*15];
    __shared__ int   sdpos[EPB];
    __shared__ float part[EPB*8], part2[EPB*8], smu[EPB], srs[EPB];
    int t = threadIdx.x;
    int id0 = blockIdx.x * EPB;

    if (t < EPB) {
        int id = id0 + t, i = id / TOPK, j = Eidx[id];
        int off = ri[i] - ri[j];
        sdpos[t] = (ch[i] == ch[j]) ? min(max(off + 32, 0), 64) : 65;
        sdist[t*25] = Dnb[id];
    }
    for (int it = t; it < EPB*15; it += 128) {
        int e = it / 15, q = it % 15;
        int id = id0 + e, i = id / TOPK, j = Eidx[id];
        sA[e*15+q] = coords[i*15+q];
        sB[e*15+q] = coords[j*15+q];
    }
    __syncthreads();
    for (int it = t; it < EPB*24; it += 128) {
        int e = it / 24, p = it % 24, a = PA[p], b = PB[p];
        float dx = sA[e*15+a*3+0] - sB[e*15+b*3+0];
        float dy = sA[e*15+a*3+1] - sB[e*15+b*3+1];
        float dz = sA[e*15+a*3+2] - sB[e*15+b*3+2];
        sdist[e*25+1+p] = sqrtf(dx*dx + dy*dy + dz*dz + 1e-6f);
    }
    __syncthreads();
    for (int it = t; it < EPB*400; it += 128) {
        int e = it / 400, c = it % 400, p = c >> 4, r = c & 15;
        float d = sdist[e*25+p];
        float x = (d - (2.0f + (float)r * (4.0f/3.0f))) * 0.8f;
        feat[e*416 + 16 + c] = __expf(-x*x);
    }
    for (int it = t; it < EPB*16; it += 128) {
        int e = it / 16, c = it % 16;
        feat[e*416 + c] = Wpos[c*66 + sdpos[e]] + bpos[c];
    }
    __syncthreads();

    float acc[EPB];
    #pragma unroll
    for (int e = 0; e < EPB; ++e) acc[e] = 0.0f;
    const float4* W4 = (const float4*)We4;
    const float4* fv = (const float4*)feat;
    int f = t;
    for (int c4 = 0; c4 < 104; ++c4) {
        float4 w = W4[c4*128 + f];
        #pragma unroll
        for (int e = 0; e < EPB; ++e) {
            float4 v = fv[e*104 + c4];
            acc[e] = fmaf(w.x, v.x, acc[e]);
            acc[e] = fmaf(w.y, v.y, acc[e]);
            acc[e] = fmaf(w.z, v.z, acc[e]);
            acc[e] = fmaf(w.w, v.w, acc[e]);
        }
    }
    __syncthreads();
    #pragma unroll
    for (int e = 0; e < EPB; ++e) feat[e*128 + f] = acc[e];   // hbuf
    __syncthreads();
    {
        int e = t >> 3, p = t & 7;
        float s = 0.f, s2 = 0.f;
        for (int q = 0; q < 16; ++q) {
            float x = feat[e*128 + p*16 + q];
            s += x; s2 += x*x;
        }
        part[e*8+p] = s; part2[e*8+p] = s2;
    }
    __syncthreads();
    if (t < EPB) {
        float s = 0.f, s2 = 0.f;
        for (int p = 0; p < 8; ++p) { s += part[t*8+p]; s2 += part2[t*8+p]; }
        float mu = s * (1.0f/128.0f);
        float var = s2 * (1.0f/128.0f) - mu*mu;
        smu[t] = mu; srs[t] = rsqrtf(var + 1e-5f);
    }
    __syncthreads();
    float gf = ge[f], bf = be[f];
    #pragma unroll
    for (int e = 0; e < EPB; ++e) {
        float x = feat[e*128 + f];
        out[OUT_E + (size_t)(id0 + e)*128 + f] = gf * (x - smu[e]) * srs[e] + bf;
    }
}

// ---------------- K5: sidechain features E_s (1280 -> 128 matvec + LN) ----------------
__global__ __launch_bounds__(128) void k_edgeS(const float* __restrict__ coords,
                                               const float* __restrict__ X,
                                               const float* __restrict__ amask,
                                               const float* __restrict__ Ws4,
                                               const int* __restrict__ Eidx,
                                               const float* __restrict__ gs,
                                               const float* __restrict__ bs,
                                               float* __restrict__ out) {
    __shared__ float feat[EPB*256];     // per-anchor chunk; reused as hbuf
    __shared__ float sA[EPB*15];
    __shared__ float sS[EPB*96];
    __shared__ float sam[EPB*32];
    __shared__ float sdist[EPB*32];
    __shared__ int   sj[EPB];
    __shared__ float part[EPB*8], part2[EPB*8], smu[EPB], srs[EPB];
    int t = threadIdx.x;
    int id0 = blockIdx.x * EPB;

    if (t < EPB) sj[t] = Eidx[id0 + t];
    __syncthreads();
    for (int it = t; it < EPB*15; it += 128) {
        int e = it / 15, q = it % 15;
        int i = (id0 + e) / TOPK;
        sA[e*15+q] = coords[i*15+q];
    }
    for (int it = t; it < EPB*96; it += 128) {
        int e = it / 96, q = it % 96;
        sS[e*96+q] = X[(sj[e]*37 + 5)*3 + q];
    }
    for (int it = t; it < EPB*32; it += 128) {
        int e = it / 32, s = it % 32;
        sam[e*32+s] = amask[sj[e]*37 + 5 + s];
    }
    __syncthreads();

    float acc[EPB];
    #pragma unroll
    for (int e = 0; e < EPB; ++e) acc[e] = 0.0f;
    const float4* W4 = (const float4*)Ws4;
    const float4* fv = (const float4*)feat;
    int f = t;

    for (int a = 0; a < 5; ++a) {
        for (int it = t; it < EPB*32; it += 128) {
            int e = it >> 5, s = it & 31;
            float dx = sA[e*15+a*3+0] - sS[e*96+s*3+0];
            float dy = sA[e*15+a*3+1] - sS[e*96+s*3+1];
            float dz = sA[e*15+a*3+2] - sS[e*96+s*3+2];
            sdist[e*32+s] = sqrtf(dx*dx + dy*dy + dz*dz + 1e-6f);
        }
        __syncthreads();
        for (int it = t; it < EPB*256; it += 128) {
            int e = it >> 8, c = it & 255, s = c >> 3, r = c & 7;
            float d = sdist[e*32+s];
            float x = (d - (2.0f + (float)r * (20.0f/7.0f))) * 0.4f;
            feat[e*256 + c] = __expf(-x*x) * sam[e*32+s];
        }
        __syncthreads();
        for (int c4 = 0; c4 < 64; ++c4) {
            float4 w = W4[(a*64 + c4)*128 + f];
            #pragma unroll
            for (int e = 0; e < EPB; ++e) {
                float4 v = fv[e*64 + c4];
                acc[e] = fmaf(w.x, v.x, acc[e]);
                acc[e] = fmaf(w.y, v.y, acc[e]);
                acc[e] = fmaf(w.z, v.z, acc[e]);
                acc[e] = fmaf(w.w, v.w, acc[e]);
            }
        }
        __syncthreads();
    }

    #pragma unroll
    for (int e = 0; e < EPB; ++e) feat[e*128 + f] = acc[e];   // hbuf
    __syncthreads();
    {
        int e = t >> 3, p = t & 7;
        float s = 0.f, s2 = 0.f;
        for (int q = 0; q < 16; ++q) {
            float x = feat[e*128 + p*16 + q];
            s += x; s2 += x*x;
        }
        part[e*8+p] = s; part2[e*8+p] = s2;
    }
    __syncthreads();
    if (t < EPB) {
        float s = 0.f, s2 = 0.f;
        for (int p = 0; p < 8; ++p) { s += part[t*8+p]; s2 += part2[t*8+p]; }
        float mu = s * (1.0f/128.0f);
        float var = s2 * (1.0f/128.0f) - mu*mu;
        smu[t] = mu; srs[t] = rsqrtf(var + 1e-5f);
    }
    __syncthreads();
    float gf = gs[f], bf = bs[f];
    #pragma unroll
    for (int e = 0; e < EPB; ++e) {
        float x = feat[e*128 + f];
        out[OUT_ES + (size_t)(id0 + e)*128 + f] = gf * (x - smu[e]) * srs[e] + bf;
    }
}

extern "C" void kernel_launch(void* const* d_in, const int* in_sizes, int n_in,
                              void* d_out, int out_size, void* d_ws, size_t ws_size,
                              hipStream_t stream) {
    (void)in_sizes; (void)n_in; (void)out_size; (void)ws_size;
    const float* X     = (const float*)d_in[0];
    // d_in[1] = L (unused, fixed 1024)
    const float* mask  = (const float*)d_in[2];
    const float* amask = (const float*)d_in[3];
    const int*   ri    = (const int*)d_in[4];
    // d_in[5] = dihedral_mask (unused by reference)
    const int*   ch    = (const int*)d_in[6];
    const float* Wpos  = (const float*)d_in[7];
    const float* bpos  = (const float*)d_in[8];
    const float* We    = (const float*)d_in[9];
    const float* ge    = (const float*)d_in[10];
    const float* be    = (const float*)d_in[11];
    const float* Ws    = (const float*)d_in[12];
    const float* gs    = (const float*)d_in[13];
    const float* bs    = (const float*)d_in[14];

    float* out    = (float*)d_out;
    float* ws     = (float*)d_ws;
    float* coords = ws + WS_COORDS;
    float* We4    = ws + WS_WE4;
    float* Ws4    = ws + WS_WS4;
    float* Dnb    = ws + WS_DNB;
    int*   Eidx   = (int*)(ws + WS_EIDX);

    k_coords<<<dim3(4), dim3(256), 0, stream>>>(X, coords);
    k_transpose<<<dim3(640), dim3(256), 0, stream>>>(We, Ws, We4, Ws4);
    k_topk<<<dim3(1024), dim3(256), 0, stream>>>(coords, mask, Dnb, Eidx, out);
    k_edgeE<<<dim3(3072), dim3(128), 0, stream>>>(coords, We4, Dnb, Eidx, ri, ch,
                                                  Wpos, bpos, ge, be, out);
    k_edgeS<<<dim3(3072), dim3(128), 0, stream>>>(coords, X, amask, Ws4, Eidx,
                                                  gs, bs, out);
}

// Round 2
// 249.502 us; speedup vs baseline: 2.8889x; 2.8889x over previous
//
#include <hip/hip_runtime.h>
#include <math.h>

#define LRES 1024
#define TOPK 48
#define NEDGE (LRES*TOPK)

typedef short short8 __attribute__((ext_vector_type(8)));
typedef float f32x4  __attribute__((ext_vector_type(4)));

// ---- output layout (floats). Tuple concat: E, E_idx, E_s, E_idx_sub ----
#define OUT_E     0
#define OUT_EIDX  6291456          // 1024*48*128
#define OUT_ES    6340608          // + 49152
#define OUT_EIDX2 12632064         // + 6291456

// ---- workspace layout (float offsets) ----
#define WS_COORDS 0                // 1024*15 floats
#define WS_DNB    15360            // 49152 floats
#define WS_EIDX   64512            // 49152 ints
#define WS_WPE    113664           // 53248 shorts (26624 floats): W_e packed B-frags
#define WS_WPS    140288           // 163840 shorts (81920 floats): W_s packed B-frags

// pair -> anchor index maps (N=0, Ca=1, C=2, O=3, Cb=4)
__constant__ int PA[24] = {0,2,3,4,1,1,1,1,0,0,0,4,4,3,0,2,3,4,2,3,4,2,3,2};
__constant__ int PB[24] = {0,2,3,4,0,2,3,4,2,3,4,2,3,2,1,1,1,1,0,0,0,4,4,3};

__device__ inline short f2bf(float f) {
    unsigned u = __float_as_uint(f);
    unsigned r = (u + 0x7FFFu + ((u >> 16) & 1u)) >> 16;
    return (short)r;
}

// ---------------- K1: per-residue coords N,Ca,C,O,Cb ----------------
__global__ void k_coords(const float* __restrict__ X, float* __restrict__ coords) {
    int r = blockIdx.x * blockDim.x + threadIdx.x;
    if (r >= LRES) return;
    const float* xr = X + r * 37 * 3;
    float N[3], Ca[3], C[3], O[3], bv[3], cv[3], av[3];
    #pragma unroll
    for (int d = 0; d < 3; ++d) {
        N[d]  = xr[0*3 + d];
        Ca[d] = xr[1*3 + d];
        C[d]  = xr[2*3 + d];
        O[d]  = xr[4*3 + d];
        bv[d] = Ca[d] - N[d];
        cv[d] = C[d] - Ca[d];
    }
    av[0] = bv[1]*cv[2] - bv[2]*cv[1];
    av[1] = bv[2]*cv[0] - bv[0]*cv[2];
    av[2] = bv[0]*cv[1] - bv[1]*cv[0];
    float* o = coords + r * 15;
    #pragma unroll
    for (int d = 0; d < 3; ++d) {
        float Cb = -0.58273431f*av[d] + 0.56802827f*bv[d] - 0.54067466f*cv[d] + Ca[d];
        o[0*3 + d] = N[d];
        o[1*3 + d] = Ca[d];
        o[2*3 + d] = C[d];
        o[3*3 + d] = O[d];
        o[4*3 + d] = Cb;
    }
}

// ---------------- K2: pack W_e / W_s into MFMA B-fragment order (bf16) ----------
// B-frag for 16x16x32: lane holds B[k = quad*8+j][n = lane&15], 8 consecutive j.
// WpE index: ((nt*13 + ks)*64 + lane)*8 + j  -> W_e[n*416 + k], n = nt*16+(lane&15)
// WpS index: ((nt*40 + ks)*64 + lane)*8 + j  -> W_s[n*1280 + k]
__global__ void k_pack(const float* __restrict__ We, const float* __restrict__ Ws,
                       short* __restrict__ WpE, short* __restrict__ WpS) {
    int t = blockIdx.x * 256 + threadIdx.x;
    if (t < 8*13*64*8) {
        int j = t & 7, lane = (t >> 3) & 63, g = t >> 9;
        int ks = g % 13, nt = g / 13;
        int n = nt*16 + (lane & 15), k = ks*32 + (lane >> 4)*8 + j;
        WpE[t] = f2bf(We[n*416 + k]);
    }
    if (t < 8*40*64*8) {
        int j = t & 7, lane = (t >> 3) & 63, g = t >> 9;
        int ks = g % 40, nt = g / 40;
        int n = nt*16 + (lane & 15), k = ks*32 + (lane >> 4)*8 + j;
        WpS[t] = f2bf(Ws[n*1280 + k]);
    }
}

// ---------------- K3: distance row + top-48 (ascending, tie->low idx) ----------------
__global__ __launch_bounds__(256) void k_topk(const float* __restrict__ coords,
                                              const float* __restrict__ mask,
                                              float* __restrict__ Dnb,
                                              int* __restrict__ Eidx,
                                              float* __restrict__ out) {
    __shared__ float sD[LRES];
    __shared__ float wv[4]; __shared__ int wi[4];
    __shared__ float sMax[4];
    int i = blockIdx.x, t = threadIdx.x;
    float cx = coords[i*15+3], cy = coords[i*15+4], cz = coords[i*15+5];
    float mi = mask[i];
    float lmax = -1e30f;
    for (int j = t; j < LRES; j += 256) {
        float dx = cx - coords[j*15+3];
        float dy = cy - coords[j*15+4];
        float dz = cz - coords[j*15+5];
        float d  = sqrtf(dx*dx + dy*dy + dz*dz + 1e-6f);
        float dm = mi * mask[j] * d;
        sD[j] = dm;
        lmax = fmaxf(lmax, dm);
    }
    for (int off = 32; off; off >>= 1) lmax = fmaxf(lmax, __shfl_down(lmax, off));
    if ((t & 63) == 0) sMax[t >> 6] = lmax;
    __syncthreads();
    float dmax = fmaxf(fmaxf(sMax[0], sMax[1]), fmaxf(sMax[2], sMax[3]));
    for (int j = t; j < LRES; j += 256) {
        float m2 = mi * mask[j];
        sD[j] += (1.0f - m2) * dmax;
    }
    __syncthreads();
    for (int it = 0; it < TOPK; ++it) {
        float bv = 3e38f; int bi = LRES;
        for (int j = t; j < LRES; j += 256) {
            float v = sD[j];
            if (v < bv) { bv = v; bi = j; }
        }
        for (int off = 32; off; off >>= 1) {
            float ov = __shfl_down(bv, off);
            int   oi = __shfl_down(bi, off);
            if (ov < bv || (ov == bv && oi < bi)) { bv = ov; bi = oi; }
        }
        if ((t & 63) == 0) { wv[t >> 6] = bv; wi[t >> 6] = bi; }
        __syncthreads();
        if (t == 0) {
            for (int w = 1; w < 4; ++w)
                if (wv[w] < bv || (wv[w] == bv && wi[w] < bi)) { bv = wv[w]; bi = wi[w]; }
            sD[bi] = 3e38f;
            int id = i*TOPK + it;
            Dnb[id]  = bv;
            Eidx[id] = bi;
            out[OUT_EIDX  + id] = (float)bi;
            out[OUT_EIDX2 + id] = (float)bi;
        }
        __syncthreads();
    }
}

// ---------------- K4: edge features E via MFMA (416 -> 128, + LN) ----------------
// 16 edges/block, 256 threads (4 waves), wave w computes N-tiles {2w, 2w+1}.
#define ASTR_E 424   // 416 + 8 pad shorts -> 212 dwords = 20 mod 32 -> 2-way (free)
__global__ __launch_bounds__(256) void k_edgeE(const float* __restrict__ coords,
                                               const short* __restrict__ WpE,
                                               const float* __restrict__ Dnb,
                                               const int* __restrict__ Eidx,
                                               const int* __restrict__ ri,
                                               const int* __restrict__ ch,
                                               const float* __restrict__ Wpos,
                                               const float* __restrict__ bpos,
                                               const float* __restrict__ ge,
                                               const float* __restrict__ be,
                                               float* __restrict__ out) {
    __shared__ short featA[16*ASTR_E];          // aliased as hbuf (16*132 floats) later
    __shared__ float sdist[16*25];
    __shared__ float sA[16*15], sB[16*15];
    __shared__ int   sdpos[16];
    __shared__ float part[16*16], part2[16*16], smu[16], srs[16];
    int t = threadIdx.x;
    int id0 = blockIdx.x * 16;

    if (t < 16) {
        int id = id0 + t, i = id / TOPK, j = Eidx[id];
        int off = ri[i] - ri[j];
        sdpos[t] = (ch[i] == ch[j]) ? min(max(off + 32, 0), 64) : 65;
        sdist[t*25] = Dnb[id];
    }
    for (int it = t; it < 16*15; it += 256) {
        int e = it / 15, q = it % 15;
        int id = id0 + e, i = id / TOPK, j = Eidx[id];
        sA[e*15+q] = coords[i*15+q];
        sB[e*15+q] = coords[j*15+q];
    }
    __syncthreads();
    for (int it = t; it < 16*24; it += 256) {
        int e = it / 24, p = it % 24, a = PA[p], b = PB[p];
        float dx = sA[e*15+a*3+0] - sB[e*15+b*3+0];
        float dy = sA[e*15+a*3+1] - sB[e*15+b*3+1];
        float dz = sA[e*15+a*3+2] - sB[e*15+b*3+2];
        sdist[e*25+1+p] = sqrtf(dx*dx + dy*dy + dz*dz + 1e-6f);
    }
    for (int it = t; it < 16*16; it += 256) {
        int e = it >> 4, c = it & 15;
        // sdpos written by t<16 before first sync; safe
        featA[e*ASTR_E + c] = f2bf(Wpos[c*66 + sdpos[e]] + bpos[c]);
    }
    __syncthreads();
    for (int it = t; it < 16*400; it += 256) {
        int e = it / 400, c = it % 400, p = c >> 4, r = c & 15;
        float d = sdist[e*25+p];
        float x = (d - (2.0f + (float)r * (4.0f/3.0f))) * 0.8f;
        featA[e*ASTR_E + 16 + c] = f2bf(__expf(-x*x));
    }
    __syncthreads();

    int w = t >> 6, lane = t & 63, quad = lane >> 4, l16 = lane & 15;
    f32x4 acc0 = {0.f,0.f,0.f,0.f}, acc1 = {0.f,0.f,0.f,0.f};
    const short8* bp = (const short8*)WpE;
    #pragma unroll 1
    for (int ks = 0; ks < 13; ++ks) {
        short8 a  = *(const short8*)&featA[l16*ASTR_E + ks*32 + quad*8];
        short8 b0 = bp[((2*w    )*13 + ks)*64 + lane];
        short8 b1 = bp[((2*w + 1)*13 + ks)*64 + lane];
        acc0 = __builtin_amdgcn_mfma_f32_16x16x32_bf16(a, b0, acc0, 0, 0, 0);
        acc1 = __builtin_amdgcn_mfma_f32_16x16x32_bf16(a, b1, acc1, 0, 0, 0);
    }
    __syncthreads();
    float* hbuf = (float*)featA;                  // 16*132 floats = 8448 B <= featA
    #pragma unroll
    for (int r = 0; r < 4; ++r) {
        int e = quad*4 + r;
        hbuf[e*132 + (2*w    )*16 + l16] = acc0[r];
        hbuf[e*132 + (2*w + 1)*16 + l16] = acc1[r];
    }
    __syncthreads();
    {
        int e = t >> 4, p = t & 15;
        float s = 0.f, s2 = 0.f;
        for (int q = 0; q < 8; ++q) {
            float x = hbuf[e*132 + p*8 + q];
            s += x; s2 += x*x;
        }
        part[e*16+p] = s; part2[e*16+p] = s2;
    }
    __syncthreads();
    if (t < 16) {
        float s = 0.f, s2 = 0.f;
        for (int p = 0; p < 16; ++p) { s += part[t*16+p]; s2 += part2[t*16+p]; }
        float mu = s * (1.0f/128.0f);
        float var = s2 * (1.0f/128.0f) - mu*mu;
        smu[t] = mu; srs[t] = rsqrtf(var + 1e-5f);
    }
    __syncthreads();
    for (int it = t; it < 16*128; it += 256) {
        int e = it >> 7, f = it & 127;
        float x = hbuf[e*132 + f];
        out[OUT_E + (size_t)(id0 + e)*128 + f] = ge[f] * (x - smu[e]) * srs[e] + be[f];
    }
}

// ---------------- K5: sidechain features E_s via MFMA (1280 -> 128, + LN) --------
// 32 edges/block, 256 threads (4 waves); wave w: N-tiles {2w,2w+1} x M-tiles {0,1}.
// K chunked per anchor: 5 chunks x 8 k-steps of 32.
#define ASTR_S 264   // 256 + 8 pad shorts -> 132 dwords = 4 mod 32 -> 2-way (free)
__global__ __launch_bounds__(256) void k_edgeS(const float* __restrict__ coords,
                                               const float* __restrict__ X,
                                               const float* __restrict__ amask,
                                               const short* __restrict__ WpS,
                                               const int* __restrict__ Eidx,
                                               const float* __restrict__ gs,
                                               const float* __restrict__ bs,
                                               float* __restrict__ out) {
    __shared__ short featA[32*ASTR_S];           // 16896 B; aliased as hbuf (32*132 f)
    __shared__ float sdist[32*32];
    __shared__ float sS[32*96];
    __shared__ float sA[32*15];
    __shared__ float sam[32*32];
    __shared__ int   sj[32];
    __shared__ float part[32*8], part2[32*8], smu[32], srs[32];
    int t = threadIdx.x;
    int id0 = blockIdx.x * 32;

    if (t < 32) sj[t] = Eidx[id0 + t];
    __syncthreads();
    for (int it = t; it < 32*15; it += 256) {
        int e = it / 15, q = it % 15;
        sA[e*15+q] = coords[((id0 + e) / TOPK)*15 + q];
    }
    for (int it = t; it < 32*96; it += 256) {
        int e = it / 96, q = it % 96;
        sS[e*96+q] = X[(sj[e]*37 + 5)*3 + q];
    }
    for (int it = t; it < 32*32; it += 256) {
        int e = it >> 5, s = it & 31;
        sam[e*32+s] = amask[sj[e]*37 + 5 + s];
    }
    __syncthreads();

    int w = t >> 6, lane = t & 63, quad = lane >> 4, l16 = lane & 15;
    f32x4 acc[2][2] = {};
    const short8* bp = (const short8*)WpS;

    for (int ach = 0; ach < 5; ++ach) {
        for (int it = t; it < 32*32; it += 256) {
            int e = it >> 5, s = it & 31;
            float dx = sA[e*15+ach*3+0] - sS[e*96+s*3+0];
            float dy = sA[e*15+ach*3+1] - sS[e*96+s*3+1];
            float dz = sA[e*15+ach*3+2] - sS[e*96+s*3+2];
            sdist[it] = sqrtf(dx*dx + dy*dy + dz*dz + 1e-6f);
        }
        __syncthreads();
        for (int it = t; it < 32*256; it += 256) {
            int e = it >> 8, c = it & 255, s = c >> 3, r = c & 7;
            float d = sdist[e*32+s];
            float x = (d - (2.0f + (float)r * (20.0f/7.0f))) * 0.4f;
            featA[e*ASTR_S + c] = f2bf(__expf(-x*x) * sam[e*32+s]);
        }
        __syncthreads();
        #pragma unroll 1
        for (int ksl = 0; ksl < 8; ++ksl) {
            int ks = ach*8 + ksl;
            short8 a0 = *(const short8*)&featA[l16*ASTR_S + ksl*32 + quad*8];
            short8 a1 = *(const short8*)&featA[(16 + l16)*ASTR_S + ksl*32 + quad*8];
            short8 b0 = bp[((2*w    )*40 + ks)*64 + lane];
            short8 b1 = bp[((2*w + 1)*40 + ks)*64 + lane];
            acc[0][0] = __builtin_amdgcn_mfma_f32_16x16x32_bf16(a0, b0, acc[0][0], 0,0,0);
            acc[0][1] = __builtin_amdgcn_mfma_f32_16x16x32_bf16(a0, b1, acc[0][1], 0,0,0);
            acc[1][0] = __builtin_amdgcn_mfma_f32_16x16x32_bf16(a1, b0, acc[1][0], 0,0,0);
            acc[1][1] = __builtin_amdgcn_mfma_f32_16x16x32_bf16(a1, b1, acc[1][1], 0,0,0);
        }
        __syncthreads();
    }

    float* hbuf = (float*)featA;                 // 32*132 floats = 16896 B == featA
    #pragma unroll
    for (int mt = 0; mt < 2; ++mt) {
        #pragma unroll
        for (int r = 0; r < 4; ++r) {
            int e = mt*16 + quad*4 + r;
            hbuf[e*132 + (2*w    )*16 + l16] = acc[mt][0][r];
            hbuf[e*132 + (2*w + 1)*16 + l16] = acc[mt][1][r];
        }
    }
    __syncthreads();
    {
        int e = t >> 3, p = t & 7;
        float s = 0.f, s2 = 0.f;
        for (int q = 0; q < 16; ++q) {
            float x = hbuf[e*132 + p*16 + q];
            s += x; s2 += x*x;
        }
        part[e*8+p] = s; part2[e*8+p] = s2;
    }
    __syncthreads();
    if (t < 32) {
        float s = 0.f, s2 = 0.f;
        for (int p = 0; p < 8; ++p) { s += part[t*8+p]; s2 += part2[t*8+p]; }
        float mu = s * (1.0f/128.0f);
        float var = s2 * (1.0f/128.0f) - mu*mu;
        smu[t] = mu; srs[t] = rsqrtf(var + 1e-5f);
    }
    __syncthreads();
    for (int it = t; it < 32*128; it += 256) {
        int e = it >> 7, f = it & 127;
        float x = hbuf[e*132 + f];
        out[OUT_ES + (size_t)(id0 + e)*128 + f] = gs[f] * (x - smu[e]) * srs[e] + bs[f];
    }
}

extern "C" void kernel_launch(void* const* d_in, const int* in_sizes, int n_in,
                              void* d_out, int out_size, void* d_ws, size_t ws_size,
                              hipStream_t stream) {
    (void)in_sizes; (void)n_in; (void)out_size; (void)ws_size;
    const float* X     = (const float*)d_in[0];
    const float* mask  = (const float*)d_in[2];
    const float* amask = (const float*)d_in[3];
    const int*   ri    = (const int*)d_in[4];
    const int*   ch    = (const int*)d_in[6];
    const float* Wpos  = (const float*)d_in[7];
    const float* bpos  = (const float*)d_in[8];
    const float* We    = (const float*)d_in[9];
    const float* ge    = (const float*)d_in[10];
    const float* be    = (const float*)d_in[11];
    const float* Ws    = (const float*)d_in[12];
    const float* gs    = (const float*)d_in[13];
    const float* bs    = (const float*)d_in[14];

    float* out    = (float*)d_out;
    float* ws     = (float*)d_ws;
    float* coords = ws + WS_COORDS;
    float* Dnb    = ws + WS_DNB;
    int*   Eidx   = (int*)(ws + WS_EIDX);
    short* WpE    = (short*)(ws + WS_WPE);
    short* WpS    = (short*)(ws + WS_WPS);

    k_coords<<<dim3(4),    dim3(256), 0, stream>>>(X, coords);
    k_pack  <<<dim3(640),  dim3(256), 0, stream>>>(We, Ws, WpE, WpS);
    k_topk  <<<dim3(1024), dim3(256), 0, stream>>>(coords, mask, Dnb, Eidx, out);
    k_edgeE <<<dim3(3072), dim3(256), 0, stream>>>(coords, WpE, Dnb, Eidx, ri, ch,
                                                   Wpos, bpos, ge, be, out);
    k_edgeS <<<dim3(1536), dim3(256), 0, stream>>>(coords, X, amask, WpS, Eidx,
                                                   gs, bs, out);
}

// Round 3
// 200.264 us; speedup vs baseline: 3.5991x; 1.2459x over previous
//
#include <hip/hip_runtime.h>
#include <math.h>

#define LRES 1024
#define TOPK 48
#define NEDGE (LRES*TOPK)

typedef short short8 __attribute__((ext_vector_type(8)));
typedef float f32x4  __attribute__((ext_vector_type(4)));

// ---- output layout (floats). Tuple concat: E, E_idx, E_s, E_idx_sub ----
#define OUT_E     0
#define OUT_EIDX  6291456          // 1024*48*128
#define OUT_ES    6340608          // + 49152
#define OUT_EIDX2 12632064         // + 6291456

// ---- workspace layout (float offsets) ----
#define WS_COORDS 0                // 1024*15 floats
#define WS_DNB    15360            // 49152 floats
#define WS_EIDX   64512            // 49152 ints
#define WS_WPE    113664           // 53248 shorts: W_e packed B-frags
#define WS_WPS    140288           // 163840 shorts: W_s packed B-frags

// RBF recurrence constants.
// edgeE: mu = 2 + r*(4/3), invsig = 0.8  -> t=(d-2)*0.8, Delta = 16/15
#define DE 1.06666667f
#define QE 0.10273976f             // exp(-2*DE^2)
// edgeS: mu = 2 + r*(20/7), invsig = 0.4 -> t=(d-2)*0.4, Delta = 8/7
#define DS 1.14285714f
#define QS 0.07337053f             // exp(-2*DS^2)

// pair -> anchor index maps (N=0, Ca=1, C=2, O=3, Cb=4)
__constant__ int PA[24] = {0,2,3,4,1,1,1,1,0,0,0,4,4,3,0,2,3,4,2,3,4,2,3,2};
__constant__ int PB[24] = {0,2,3,4,0,2,3,4,2,3,4,2,3,2,1,1,1,1,0,0,0,4,4,3};

__device__ inline short f2bf(float f) {           // RNE, used off hot path (weights)
    unsigned u = __float_as_uint(f);
    unsigned r = (u + 0x7FFFu + ((u >> 16) & 1u)) >> 16;
    return (short)r;
}

// pack 8 floats -> short8 bf16 by truncation: 1 v_perm per 2 values
__device__ inline short8 pack8(const float* fv) {
    union { short8 s; unsigned u[4]; } r;
    #pragma unroll
    for (int i = 0; i < 4; ++i)
        r.u[i] = __builtin_amdgcn_perm(__float_as_uint(fv[2*i+1]),
                                       __float_as_uint(fv[2*i]), 0x07060302u);
    return r.s;
}

// ---------------- K0: fused weight pack + coords ----------------
__global__ void k_prep(const float* __restrict__ X, const float* __restrict__ We,
                       const float* __restrict__ Ws, float* __restrict__ coords,
                       short* __restrict__ WpE, short* __restrict__ WpS) {
    if (blockIdx.x < 640) {
        int t = blockIdx.x * 256 + threadIdx.x;
        if (t < 8*13*64*8) {
            int j = t & 7, lane = (t >> 3) & 63, g = t >> 9;
            int ks = g % 13, nt = g / 13;
            int n = nt*16 + (lane & 15), k = ks*32 + (lane >> 4)*8 + j;
            WpE[t] = f2bf(We[n*416 + k]);
        }
        if (t < 8*40*64*8) {
            int j = t & 7, lane = (t >> 3) & 63, g = t >> 9;
            int ks = g % 40, nt = g / 40;
            int n = nt*16 + (lane & 15), k = ks*32 + (lane >> 4)*8 + j;
            WpS[t] = f2bf(Ws[n*1280 + k]);
        }
    } else {
        int r = (blockIdx.x - 640) * 256 + threadIdx.x;
        if (r >= LRES) return;
        const float* xr = X + r * 37 * 3;
        float N[3], Ca[3], C[3], O[3], bv[3], cv[3], av[3];
        #pragma unroll
        for (int d = 0; d < 3; ++d) {
            N[d]  = xr[0*3 + d];  Ca[d] = xr[1*3 + d];
            C[d]  = xr[2*3 + d];  O[d]  = xr[4*3 + d];
            bv[d] = Ca[d] - N[d]; cv[d] = C[d] - Ca[d];
        }
        av[0] = bv[1]*cv[2] - bv[2]*cv[1];
        av[1] = bv[2]*cv[0] - bv[0]*cv[2];
        av[2] = bv[0]*cv[1] - bv[1]*cv[0];
        float* o = coords + r * 15;
        #pragma unroll
        for (int d = 0; d < 3; ++d) {
            float Cb = -0.58273431f*av[d] + 0.56802827f*bv[d] - 0.54067466f*cv[d] + Ca[d];
            o[0*3+d] = N[d]; o[1*3+d] = Ca[d]; o[2*3+d] = C[d];
            o[3*3+d] = O[d]; o[4*3+d] = Cb;
        }
    }
}

// ---------------- K1: top-48 per row, one wave per row ----------------
__global__ __launch_bounds__(256) void k_topk(const float* __restrict__ X,
                                              const float* __restrict__ mask,
                                              float* __restrict__ Dnb,
                                              int* __restrict__ Eidx,
                                              float* __restrict__ out) {
    __shared__ float sCa[LRES*3];
    __shared__ float sM[LRES];
    int t = threadIdx.x;
    for (int j = t; j < LRES; j += 256) {
        sCa[j*3+0] = X[j*111 + 3];
        sCa[j*3+1] = X[j*111 + 4];
        sCa[j*3+2] = X[j*111 + 5];
        sM[j] = mask[j];
    }
    __syncthreads();
    int w = t >> 6, lane = t & 63;
    int i = blockIdx.x * 4 + w;
    float cx = sCa[i*3], cy = sCa[i*3+1], cz = sCa[i*3+2];
    float mi = sM[i];
    float dv[16], m2v[16];
    float lmax = -1e30f;
    #pragma unroll
    for (int s = 0; s < 16; ++s) {
        int j = s*64 + lane;
        float dx = cx - sCa[j*3], dy = cy - sCa[j*3+1], dz = cz - sCa[j*3+2];
        float d  = sqrtf(dx*dx + dy*dy + dz*dz + 1e-6f);
        float m2 = mi * sM[j];
        dv[s] = m2 * d; m2v[s] = m2;
        lmax = fmaxf(lmax, dv[s]);
    }
    #pragma unroll
    for (int off = 32; off; off >>= 1) lmax = fmaxf(lmax, __shfl_xor(lmax, off));
    unsigned long long key[16];
    unsigned long long mkey = ~0ull; int mslot = 0;
    #pragma unroll
    for (int s = 0; s < 16; ++s) {
        float dadj = dv[s] + (1.0f - m2v[s]) * lmax;
        key[s] = (((unsigned long long)__float_as_uint(dadj)) << 10) | (unsigned)(s*64 + lane);
        if (key[s] < mkey) { mkey = key[s]; mslot = s; }
    }
    for (int it = 0; it < TOPK; ++it) {
        unsigned long long wk = mkey;
        #pragma unroll
        for (int off = 32; off; off >>= 1) {
            unsigned long long o = __shfl_xor(wk, off);
            wk = (o < wk) ? o : wk;
        }
        if (lane == 0) {
            int j = (int)(wk & 1023u);
            int id = i*TOPK + it;
            Dnb[id]  = __uint_as_float((unsigned)(wk >> 10));
            Eidx[id] = j;
            out[OUT_EIDX  + id] = (float)j;
            out[OUT_EIDX2 + id] = (float)j;
        }
        if (mkey == wk) {
            key[mslot] = ~0ull;
            mkey = ~0ull;
            #pragma unroll
            for (int s = 0; s < 16; ++s)
                if (key[s] < mkey) { mkey = key[s]; mslot = s; }
        }
    }
}

// ---------------- K2: edge features E, inline A-frags + K-split waves ----------
// 32 edges/block, 4 waves; wave w does ksteps {w, w+4, ...} of 13, all 8 N-tiles.
__global__ __launch_bounds__(256, 3) void k_edgeE(const float* __restrict__ coords,
                                                  const short* __restrict__ WpE,
                                                  const float* __restrict__ Dnb,
                                                  const int* __restrict__ Eidx,
                                                  const int* __restrict__ ri,
                                                  const int* __restrict__ ch,
                                                  const float* __restrict__ Wpos,
                                                  const float* __restrict__ bpos,
                                                  const float* __restrict__ ge,
                                                  const float* __restrict__ be,
                                                  float* __restrict__ out) {
    __shared__ float sA[32*15], sB[32*15];
    __shared__ float u_hbuf[32*132];        // setup: sdist(32*27) + sposf(32*17) at +864
    __shared__ int   sdpos[32];
    __shared__ float part[32*8], part2[32*8], smu[32], srs[32];
    float* sdist = u_hbuf;                  // stride 27
    float* sposf = u_hbuf + 32*27;          // stride 17
    int t = threadIdx.x;
    int id0 = blockIdx.x * 32;

    if (t < 32) {
        int id = id0 + t, i = id / TOPK, j = Eidx[id];
        int off = ri[i] - ri[j];
        sdpos[t] = (ch[i] == ch[j]) ? min(max(off + 32, 0), 64) : 65;
        sdist[t*27] = Dnb[id];
    }
    for (int it = t; it < 32*15; it += 256) {
        int e = it / 15, q = it % 15;
        int id = id0 + e, i = id / TOPK, j = Eidx[id];
        sA[e*15+q] = coords[i*15+q];
        sB[e*15+q] = coords[j*15+q];
    }
    __syncthreads();
    for (int it = t; it < 32*24; it += 256) {
        int e = it / 24, p = it % 24, a = PA[p], b = PB[p];
        float dx = sA[e*15+a*3+0] - sB[e*15+b*3+0];
        float dy = sA[e*15+a*3+1] - sB[e*15+b*3+1];
        float dz = sA[e*15+a*3+2] - sB[e*15+b*3+2];
        sdist[e*27 + 1 + p] = sqrtf(dx*dx + dy*dy + dz*dz + 1e-6f);
    }
    for (int it = t; it < 32*16; it += 256) {
        int e = it >> 4, c = it & 15;
        sposf[e*17 + c] = Wpos[c*66 + sdpos[e]] + bpos[c];
    }
    __syncthreads();

    int w = t >> 6, lane = t & 63, quad = lane >> 4, l16 = lane & 15;
    f32x4 acc[2][8] = {};
    const short8* bp = (const short8*)WpE;
    float rb = (quad & 1) ? 8.0f*DE : 0.0f;

    for (int ks = w; ks < 13; ks += 4) {
        short8 afrag[2];
        #pragma unroll
        for (int mt = 0; mt < 2; ++mt) {
            int e = mt*16 + l16;
            float fv[8];
            if (ks == 0 && quad < 2) {
                #pragma unroll
                for (int j = 0; j < 8; ++j) fv[j] = sposf[e*17 + quad*8 + j];
            } else {
                int p = (ks == 0) ? 0 : (2*ks - 1 + (quad >> 1));
                float d = sdist[e*27 + p];
                float u = fmaf(d, 0.8f, -1.6f) - rb;
                float e0 = __expf(-u*u);
                float g  = __expf(DE*(u + u - DE));
                fv[0] = e0;
                #pragma unroll
                for (int r = 1; r < 8; ++r) { e0 *= g; g *= QE; fv[r] = e0; }
            }
            afrag[mt] = pack8(fv);
        }
        #pragma unroll
        for (int nt = 0; nt < 8; ++nt) {
            short8 b = bp[(nt*13 + ks)*64 + lane];
            acc[0][nt] = __builtin_amdgcn_mfma_f32_16x16x32_bf16(afrag[0], b, acc[0][nt], 0,0,0);
            acc[1][nt] = __builtin_amdgcn_mfma_f32_16x16x32_bf16(afrag[1], b, acc[1][nt], 0,0,0);
        }
    }

    // serial cross-wave reduce into hbuf
    float* hbuf = u_hbuf;                    // 32*132
    __syncthreads();
    for (int ww = 0; ww < 4; ++ww) {
        if (w == ww) {
            #pragma unroll
            for (int mt = 0; mt < 2; ++mt)
            #pragma unroll
            for (int nt = 0; nt < 8; ++nt)
            #pragma unroll
            for (int r = 0; r < 4; ++r) {
                int e = mt*16 + quad*4 + r;
                float* p = &hbuf[e*132 + nt*16 + l16];
                if (ww == 0) *p = acc[mt][nt][r]; else *p += acc[mt][nt][r];
            }
        }
        __syncthreads();
    }
    {
        int e = t >> 3, p = t & 7;
        float s = 0.f, s2 = 0.f;
        #pragma unroll
        for (int q = 0; q < 16; ++q) {
            float x = hbuf[e*132 + p*16 + q];
            s += x; s2 += x*x;
        }
        part[e*8+p] = s; part2[e*8+p] = s2;
    }
    __syncthreads();
    if (t < 32) {
        float s = 0.f, s2 = 0.f;
        #pragma unroll
        for (int p = 0; p < 8; ++p) { s += part[t*8+p]; s2 += part2[t*8+p]; }
        float mu = s * (1.0f/128.0f);
        float var = s2 * (1.0f/128.0f) - mu*mu;
        smu[t] = mu; srs[t] = rsqrtf(var + 1e-5f);
    }
    __syncthreads();
    for (int it = t; it < 32*128; it += 256) {
        int e = it >> 7, f = it & 127;
        float x = hbuf[e*132 + f];
        out[OUT_E + (size_t)(id0 + e)*128 + f] = ge[f] * (x - smu[e]) * srs[e] + be[f];
    }
}

// ---------------- K3: sidechain features E_s, inline A-frags + K-split ----------
// 32 edges/block, 4 waves; wave w: ksteps {w, w+4, ..., w+36} of 40, all 8 N-tiles.
__global__ __launch_bounds__(256, 3) void k_edgeS(const float* __restrict__ coords,
                                                  const float* __restrict__ X,
                                                  const float* __restrict__ amask,
                                                  const short* __restrict__ WpS,
                                                  const int* __restrict__ Eidx,
                                                  const float* __restrict__ gs,
                                                  const float* __restrict__ bs,
                                                  float* __restrict__ out) {
    __shared__ float sA[32*15];
    __shared__ float u_hbuf[32*132];         // sS (stride 100) during main; hbuf after
    __shared__ float sam[32*35];
    __shared__ int   sj[32];
    __shared__ float part[32*8], part2[32*8], smu[32], srs[32];
    float* sS = u_hbuf;                      // 32*100 = 3200 <= 4224
    int t = threadIdx.x;
    int id0 = blockIdx.x * 32;

    if (t < 32) sj[t] = Eidx[id0 + t];
    __syncthreads();
    for (int it = t; it < 32*15; it += 256) {
        int e = it / 15, q = it % 15;
        sA[e*15+q] = coords[((id0 + e) / TOPK)*15 + q];
    }
    for (int it = t; it < 32*96; it += 256) {
        int e = it / 96, q = it % 96;
        sS[e*100 + q] = X[(sj[e]*37 + 5)*3 + q];
    }
    for (int it = t; it < 32*32; it += 256) {
        int e = it >> 5, s = it & 31;
        sam[e*35 + s] = amask[sj[e]*37 + 5 + s];
    }
    __syncthreads();

    int w = t >> 6, lane = t & 63, quad = lane >> 4, l16 = lane & 15;
    f32x4 acc[2][8] = {};
    const short8* bp = (const short8*)WpS;

    for (int ks = w; ks < 40; ks += 4) {
        int ach = ks >> 3, s = (ks & 7)*4 + quad;
        short8 afrag[2];
        #pragma unroll
        for (int mt = 0; mt < 2; ++mt) {
            int e = mt*16 + l16;
            float dx = sA[e*15 + ach*3 + 0] - sS[e*100 + s*3 + 0];
            float dy = sA[e*15 + ach*3 + 1] - sS[e*100 + s*3 + 1];
            float dz = sA[e*15 + ach*3 + 2] - sS[e*100 + s*3 + 2];
            float d  = sqrtf(dx*dx + dy*dy + dz*dz + 1e-6f);
            float u  = fmaf(d, 0.4f, -0.8f);
            float e0 = __expf(-u*u) * sam[e*35 + s];
            float g  = __expf(DS*(u + u - DS));
            float fv[8];
            fv[0] = e0;
            #pragma unroll
            for (int r = 1; r < 8; ++r) { e0 *= g; g *= QS; fv[r] = e0; }
            afrag[mt] = pack8(fv);
        }
        #pragma unroll
        for (int nt = 0; nt < 8; ++nt) {
            short8 b = bp[(nt*40 + ks)*64 + lane];
            acc[0][nt] = __builtin_amdgcn_mfma_f32_16x16x32_bf16(afrag[0], b, acc[0][nt], 0,0,0);
            acc[1][nt] = __builtin_amdgcn_mfma_f32_16x16x32_bf16(afrag[1], b, acc[1][nt], 0,0,0);
        }
    }

    float* hbuf = u_hbuf;
    __syncthreads();
    for (int ww = 0; ww < 4; ++ww) {
        if (w == ww) {
            #pragma unroll
            for (int mt = 0; mt < 2; ++mt)
            #pragma unroll
            for (int nt = 0; nt < 8; ++nt)
            #pragma unroll
            for (int r = 0; r < 4; ++r) {
                int e = mt*16 + quad*4 + r;
                float* p = &hbuf[e*132 + nt*16 + l16];
                if (ww == 0) *p = acc[mt][nt][r]; else *p += acc[mt][nt][r];
            }
        }
        __syncthreads();
    }
    {
        int e = t >> 3, p = t & 7;
        float s = 0.f, s2 = 0.f;
        #pragma unroll
        for (int q = 0; q < 16; ++q) {
            float x = hbuf[e*132 + p*16 + q];
            s += x; s2 += x*x;
        }
        part[e*8+p] = s; part2[e*8+p] = s2;
    }
    __syncthreads();
    if (t < 32) {
        float s = 0.f, s2 = 0.f;
        #pragma unroll
        for (int p = 0; p < 8; ++p) { s += part[t*8+p]; s2 += part2[t*8+p]; }
        float mu = s * (1.0f/128.0f);
        float var = s2 * (1.0f/128.0f) - mu*mu;
        smu[t] = mu; srs[t] = rsqrtf(var + 1e-5f);
    }
    __syncthreads();
    for (int it = t; it < 32*128; it += 256) {
        int e = it >> 7, f = it & 127;
        float x = hbuf[e*132 + f];
        out[OUT_ES + (size_t)(id0 + e)*128 + f] = gs[f] * (x - smu[e]) * srs[e] + bs[f];
    }
}

extern "C" void kernel_launch(void* const* d_in, const int* in_sizes, int n_in,
                              void* d_out, int out_size, void* d_ws, size_t ws_size,
                              hipStream_t stream) {
    (void)in_sizes; (void)n_in; (void)out_size; (void)ws_size;
    const float* X     = (const float*)d_in[0];
    const float* mask  = (const float*)d_in[2];
    const float* amask = (const float*)d_in[3];
    const int*   ri    = (const int*)d_in[4];
    const int*   ch    = (const int*)d_in[6];
    const float* Wpos  = (const float*)d_in[7];
    const float* bpos  = (const float*)d_in[8];
    const float* We    = (const float*)d_in[9];
    const float* ge    = (const float*)d_in[10];
    const float* be    = (const float*)d_in[11];
    const float* Ws    = (const float*)d_in[12];
    const float* gs    = (const float*)d_in[13];
    const float* bs    = (const float*)d_in[14];

    float* out    = (float*)d_out;
    float* ws     = (float*)d_ws;
    float* coords = ws + WS_COORDS;
    float* Dnb    = ws + WS_DNB;
    int*   Eidx   = (int*)(ws + WS_EIDX);
    short* WpE    = (short*)(ws + WS_WPE);
    short* WpS    = (short*)(ws + WS_WPS);

    k_prep <<<dim3(644),  dim3(256), 0, stream>>>(X, We, Ws, coords, WpE, WpS);
    k_topk <<<dim3(256),  dim3(256), 0, stream>>>(X, mask, Dnb, Eidx, out);
    k_edgeE<<<dim3(1536), dim3(256), 0, stream>>>(coords, WpE, Dnb, Eidx, ri, ch,
                                                  Wpos, bpos, ge, be, out);
    k_edgeS<<<dim3(1536), dim3(256), 0, stream>>>(coords, X, amask, WpS, Eidx,
                                                  gs, bs, out);
}

// Round 4
// 187.579 us; speedup vs baseline: 3.8425x; 1.0676x over previous
//
#include <hip/hip_runtime.h>
#include <math.h>

#define LRES 1024
#define TOPK 48
#define NEDGE (LRES*TOPK)

typedef short short8 __attribute__((ext_vector_type(8)));
typedef float f32x4  __attribute__((ext_vector_type(4)));

// ---- output layout (floats). Tuple concat: E, E_idx, E_s, E_idx_sub ----
#define OUT_E     0
#define OUT_EIDX  6291456          // 1024*48*128
#define OUT_ES    6340608          // + 49152
#define OUT_EIDX2 12632064         // + 6291456

// ---- workspace layout (float offsets) ----
#define WS_COORDS 0                // 1024*15 floats
#define WS_DNB    15360            // 49152 floats
#define WS_EIDX   64512            // 49152 ints
#define WS_WPE    113664           // 53248 shorts: W_e packed B-frags
#define WS_WPS    140288           // 163840 shorts: W_s packed B-frags

// RBF recurrence constants.
// edgeE: mu = 2 + r*(4/3), invsig = 0.8  -> u=(d-2)*0.8, Delta = 16/15
#define DE 1.06666667f
#define QE 0.10273976f             // exp(-2*DE^2)
// edgeS: mu = 2 + r*(20/7), invsig = 0.4 -> u=(d-2)*0.4, Delta = 8/7
#define DS 1.14285714f
#define QS 0.07337053f             // exp(-2*DS^2)

// pair -> anchor index maps (N=0, Ca=1, C=2, O=3, Cb=4)
__constant__ int PA[24] = {0,2,3,4,1,1,1,1,0,0,0,4,4,3,0,2,3,4,2,3,4,2,3,2};
__constant__ int PB[24] = {0,2,3,4,0,2,3,4,2,3,4,2,3,2,1,1,1,1,0,0,0,4,4,3};

__device__ inline short f2bf(float f) {           // RNE, off hot path (weights)
    unsigned u = __float_as_uint(f);
    unsigned r = (u + 0x7FFFu + ((u >> 16) & 1u)) >> 16;
    return (short)r;
}

// pack 8 floats -> short8 bf16 by truncation: 1 v_perm per 2 values
__device__ inline short8 pack8(const float* fv) {
    union { short8 s; unsigned u[4]; } r;
    #pragma unroll
    for (int i = 0; i < 4; ++i)
        r.u[i] = __builtin_amdgcn_perm(__float_as_uint(fv[2*i+1]),
                                       __float_as_uint(fv[2*i]), 0x07060302u);
    return r.s;
}

// ============ K_PRE: topk (blocks 0..255) | pack (256..895) | coords (896..899) =====
__global__ __launch_bounds__(256) void k_pre(const float* __restrict__ X,
                                             const float* __restrict__ mask,
                                             const float* __restrict__ We,
                                             const float* __restrict__ Ws,
                                             float* __restrict__ coords,
                                             short* __restrict__ WpE,
                                             short* __restrict__ WpS,
                                             float* __restrict__ Dnb,
                                             int* __restrict__ Eidx,
                                             float* __restrict__ out) {
    int blk = blockIdx.x, t = threadIdx.x;
    if (blk < 256) {
        // ---------------- top-48 per row, one wave per row ----------------
        __shared__ float sCa[LRES*3];
        __shared__ float sM[LRES];
        for (int j = t; j < LRES; j += 256) {
            sCa[j*3+0] = X[j*111 + 3];
            sCa[j*3+1] = X[j*111 + 4];
            sCa[j*3+2] = X[j*111 + 5];
            sM[j] = mask[j];
        }
        __syncthreads();
        int w = t >> 6, lane = t & 63;
        int i = blk * 4 + w;
        float cx = sCa[i*3], cy = sCa[i*3+1], cz = sCa[i*3+2];
        float mi = sM[i];
        float dv[16], m2v[16];
        float lmax = -1e30f;
        #pragma unroll
        for (int s = 0; s < 16; ++s) {
            int j = s*64 + lane;
            float dx = cx - sCa[j*3], dy = cy - sCa[j*3+1], dz = cz - sCa[j*3+2];
            float d  = __builtin_amdgcn_sqrtf(dx*dx + dy*dy + dz*dz + 1e-6f);
            float m2 = mi * sM[j];
            dv[s] = m2 * d; m2v[s] = m2;
            lmax = fmaxf(lmax, dv[s]);
        }
        #pragma unroll
        for (int off = 32; off; off >>= 1) lmax = fmaxf(lmax, __shfl_xor(lmax, off));
        unsigned long long key[16];
        unsigned long long mkey = ~0ull; int mslot = 0;
        #pragma unroll
        for (int s = 0; s < 16; ++s) {
            float dadj = dv[s] + (1.0f - m2v[s]) * lmax;
            key[s] = (((unsigned long long)__float_as_uint(dadj)) << 10) | (unsigned)(s*64 + lane);
            if (key[s] < mkey) { mkey = key[s]; mslot = s; }
        }
        for (int it = 0; it < TOPK; ++it) {
            unsigned long long wk = mkey;
            #pragma unroll
            for (int off = 32; off; off >>= 1) {
                unsigned long long o = __shfl_xor(wk, off);
                wk = (o < wk) ? o : wk;
            }
            if (lane == 0) {
                int j = (int)(wk & 1023u);
                int id = i*TOPK + it;
                Dnb[id]  = __uint_as_float((unsigned)(wk >> 10));
                Eidx[id] = j;
                out[OUT_EIDX  + id] = (float)j;
                out[OUT_EIDX2 + id] = (float)j;
            }
            if (mkey == wk) {
                key[mslot] = ~0ull;
                mkey = ~0ull;
                #pragma unroll
                for (int s = 0; s < 16; ++s)
                    if (key[s] < mkey) { mkey = key[s]; mslot = s; }
            }
        }
    } else if (blk < 896) {
        // ---------------- pack W_e / W_s into MFMA B-fragment order ----------------
        int g = (blk - 256) * 256 + t;
        if (g < 8*13*64*8) {
            int j = g & 7, lane = (g >> 3) & 63, gg = g >> 9;
            int ks = gg % 13, nt = gg / 13;
            int n = nt*16 + (lane & 15), k = ks*32 + (lane >> 4)*8 + j;
            WpE[g] = f2bf(We[n*416 + k]);
        }
        if (g < 8*40*64*8) {
            int j = g & 7, lane = (g >> 3) & 63, gg = g >> 9;
            int ks = gg % 40, nt = gg / 40;
            int n = nt*16 + (lane & 15), k = ks*32 + (lane >> 4)*8 + j;
            WpS[g] = f2bf(Ws[n*1280 + k]);
        }
    } else {
        // ---------------- per-residue coords N,Ca,C,O,Cb ----------------
        int r = (blk - 896) * 256 + t;
        if (r >= LRES) return;
        const float* xr = X + r * 111;
        float N[3], Ca[3], C[3], O[3], bv[3], cv[3], av[3];
        #pragma unroll
        for (int d = 0; d < 3; ++d) {
            N[d]  = xr[0*3 + d];  Ca[d] = xr[1*3 + d];
            C[d]  = xr[2*3 + d];  O[d]  = xr[4*3 + d];
            bv[d] = Ca[d] - N[d]; cv[d] = C[d] - Ca[d];
        }
        av[0] = bv[1]*cv[2] - bv[2]*cv[1];
        av[1] = bv[2]*cv[0] - bv[0]*cv[2];
        av[2] = bv[0]*cv[1] - bv[1]*cv[0];
        float* o = coords + r * 15;
        #pragma unroll
        for (int d = 0; d < 3; ++d) {
            float Cb = -0.58273431f*av[d] + 0.56802827f*bv[d] - 0.54067466f*cv[d] + Ca[d];
            o[0*3+d] = N[d]; o[1*3+d] = Ca[d]; o[2*3+d] = C[d];
            o[3*3+d] = O[d]; o[4*3+d] = Cb;
        }
    }
}

// ============ K_EDGE: edgeS (blocks 0..1535) | edgeE (1536..3071) ============
// Both: 32 edges/block, 4 waves, K-split across waves, 8 N-tiles each.
__global__ __launch_bounds__(256, 2) void k_edge(const float* __restrict__ coords,
                                                 const float* __restrict__ X,
                                                 const float* __restrict__ amask,
                                                 const short* __restrict__ WpE,
                                                 const short* __restrict__ WpS,
                                                 const float* __restrict__ Dnb,
                                                 const int* __restrict__ Eidx,
                                                 const int* __restrict__ ri,
                                                 const int* __restrict__ ch,
                                                 const float* __restrict__ Wpos,
                                                 const float* __restrict__ bpos,
                                                 const float* __restrict__ ge,
                                                 const float* __restrict__ be,
                                                 const float* __restrict__ gs,
                                                 const float* __restrict__ bs,
                                                 float* __restrict__ out) {
    __shared__ float smem[5808];
    int t = threadIdx.x;
    int w = t >> 6, lane = t & 63, quad = lane >> 4, l16 = lane & 15;

    if (blockIdx.x < 1536) {
        // =============== edgeS: 1280 -> 128 matvec + LN ===============
        float* u_hbuf = smem;                 // 32*132 = 4224
        float* sA3    = smem + 4224;          // 45
        float* part   = smem + 4272;          // 256
        float* part2  = smem + 4528;          // 256
        float* smu    = smem + 4784;          // 32
        float* srs    = smem + 4816;          // 32
        int id0 = blockIdx.x * 32;
        int i0 = id0 / TOPK;

        if (t < 45) {
            int rr = i0 + t / 15;
            if (rr > LRES-1) rr = LRES-1;
            sA3[t] = coords[rr*15 + t%15];
        }
        // per-lane register operands
        int s1 = 4*w + quad;                  // sidechain atom for half 0
        float S[2][2][3], am[2][2];
        int im[2];
        #pragma unroll
        for (int mt = 0; mt < 2; ++mt) {
            int id = id0 + mt*16 + l16;
            int j  = Eidx[id];
            im[mt] = id / TOPK;
            const float* xp = X + (j*37 + 5)*3;
            const float* ap = amask + j*37 + 5;
            #pragma unroll
            for (int h = 0; h < 2; ++h) {
                int s = s1 + h*16;
                S[mt][h][0] = xp[s*3+0];
                S[mt][h][1] = xp[s*3+1];
                S[mt][h][2] = xp[s*3+2];
                am[mt][h]   = ap[s];
            }
        }
        __syncthreads();

        f32x4 acc[2][8] = {};
        const short8* bp = (const short8*)WpS;

        for (int a = 0; a < 5; ++a) {
            float A[2][3];
            #pragma unroll
            for (int mt = 0; mt < 2; ++mt) {
                int base = (im[mt] - i0)*15 + a*3;
                A[mt][0] = sA3[base+0];
                A[mt][1] = sA3[base+1];
                A[mt][2] = sA3[base+2];
            }
            #pragma unroll
            for (int h = 0; h < 2; ++h) {
                int ks = a*8 + w + h*4;
                short8 afrag[2];
                #pragma unroll
                for (int mt = 0; mt < 2; ++mt) {
                    float dx = A[mt][0] - S[mt][h][0];
                    float dy = A[mt][1] - S[mt][h][1];
                    float dz = A[mt][2] - S[mt][h][2];
                    float d  = __builtin_amdgcn_sqrtf(fmaf(dz,dz,fmaf(dy,dy,fmaf(dx,dx,1e-6f))));
                    float u  = fmaf(d, 0.4f, -0.8f);
                    float e0 = __expf(-u*u) * am[mt][h];
                    float g  = __expf(fmaf(2.0f*DS, u, -DS*DS));
                    float fv[8];
                    fv[0] = e0;
                    #pragma unroll
                    for (int r = 1; r < 8; ++r) { e0 *= g; g *= QS; fv[r] = e0; }
                    afrag[mt] = pack8(fv);
                }
                #pragma unroll
                for (int nt = 0; nt < 8; ++nt) {
                    short8 b = bp[(nt*40 + ks)*64 + lane];
                    acc[0][nt] = __builtin_amdgcn_mfma_f32_16x16x32_bf16(afrag[0], b, acc[0][nt], 0,0,0);
                    acc[1][nt] = __builtin_amdgcn_mfma_f32_16x16x32_bf16(afrag[1], b, acc[1][nt], 0,0,0);
                }
            }
        }

        float* hbuf = u_hbuf;
        __syncthreads();
        for (int ww = 0; ww < 4; ++ww) {
            if (w == ww) {
                #pragma unroll
                for (int mt = 0; mt < 2; ++mt)
                #pragma unroll
                for (int nt = 0; nt < 8; ++nt)
                #pragma unroll
                for (int r = 0; r < 4; ++r) {
                    int e = mt*16 + quad*4 + r;
                    float* p = &hbuf[e*132 + nt*16 + l16];
                    if (ww == 0) *p = acc[mt][nt][r]; else *p += acc[mt][nt][r];
                }
            }
            __syncthreads();
        }
        {
            int e = t >> 3, p = t & 7;
            float s = 0.f, s2 = 0.f;
            #pragma unroll
            for (int q = 0; q < 16; ++q) {
                float x = hbuf[e*132 + p*16 + q];
                s += x; s2 += x*x;
            }
            part[e*8+p] = s; part2[e*8+p] = s2;
        }
        __syncthreads();
        if (t < 32) {
            float s = 0.f, s2 = 0.f;
            #pragma unroll
            for (int p = 0; p < 8; ++p) { s += part[t*8+p]; s2 += part2[t*8+p]; }
            float mu = s * (1.0f/128.0f);
            float var = s2 * (1.0f/128.0f) - mu*mu;
            smu[t] = mu; srs[t] = rsqrtf(var + 1e-5f);
        }
        __syncthreads();
        for (int it = t; it < 32*128; it += 256) {
            int e = it >> 7, f = it & 127;
            float x = hbuf[e*132 + f];
            out[OUT_ES + (size_t)(id0 + e)*128 + f] = gs[f] * (x - smu[e]) * srs[e] + bs[f];
        }
    } else {
        // =============== edgeE: 416 -> 128 matvec + LN ===============
        float* sA     = smem;                 // 480
        float* sB     = smem + 480;           // 480
        float* u_hbuf = smem + 960;           // 4224 (sdist 32*27 + sposf 32*17 inside)
        float* part   = smem + 5184;          // 256
        float* part2  = smem + 5440;          // 256
        float* smu    = smem + 5696;          // 32
        float* srs    = smem + 5728;          // 32
        int*   sdpos  = (int*)(smem + 5760);  // 32
        float* sdist  = u_hbuf;               // stride 27
        float* sposf  = u_hbuf + 32*27;       // stride 17
        int id0 = (blockIdx.x - 1536) * 32;

        if (t < 32) {
            int id = id0 + t, i = id / TOPK, j = Eidx[id];
            int off = ri[i] - ri[j];
            sdpos[t] = (ch[i] == ch[j]) ? min(max(off + 32, 0), 64) : 65;
            sdist[t*27] = Dnb[id];
        }
        for (int it = t; it < 32*15; it += 256) {
            int e = it / 15, q = it % 15;
            int id = id0 + e, i = id / TOPK, j = Eidx[id];
            sA[e*15+q] = coords[i*15+q];
            sB[e*15+q] = coords[j*15+q];
        }
        __syncthreads();
        for (int it = t; it < 32*24; it += 256) {
            int e = it / 24, p = it % 24, a = PA[p], b = PB[p];
            float dx = sA[e*15+a*3+0] - sB[e*15+b*3+0];
            float dy = sA[e*15+a*3+1] - sB[e*15+b*3+1];
            float dz = sA[e*15+a*3+2] - sB[e*15+b*3+2];
            sdist[e*27 + 1 + p] = __builtin_amdgcn_sqrtf(dx*dx + dy*dy + dz*dz + 1e-6f);
        }
        for (int it = t; it < 32*16; it += 256) {
            int e = it >> 4, c = it & 15;
            sposf[e*17 + c] = Wpos[c*66 + sdpos[e]] + bpos[c];
        }
        __syncthreads();

        f32x4 acc[2][8] = {};
        const short8* bp = (const short8*)WpE;
        float rb = (quad & 1) ? 8.0f*DE : 0.0f;

        for (int ks = w; ks < 13; ks += 4) {
            short8 afrag[2];
            #pragma unroll
            for (int mt = 0; mt < 2; ++mt) {
                int e = mt*16 + l16;
                float fv[8];
                if (ks == 0 && quad < 2) {
                    #pragma unroll
                    for (int j = 0; j < 8; ++j) fv[j] = sposf[e*17 + quad*8 + j];
                } else {
                    int p = (ks == 0) ? 0 : (2*ks - 1 + (quad >> 1));
                    float d = sdist[e*27 + p];
                    float u = fmaf(d, 0.8f, -1.6f) - rb;
                    float e0 = __expf(-u*u);
                    float g  = __expf(fmaf(2.0f*DE, u, -DE*DE));
                    fv[0] = e0;
                    #pragma unroll
                    for (int r = 1; r < 8; ++r) { e0 *= g; g *= QE; fv[r] = e0; }
                }
                afrag[mt] = pack8(fv);
            }
            #pragma unroll
            for (int nt = 0; nt < 8; ++nt) {
                short8 b = bp[(nt*13 + ks)*64 + lane];
                acc[0][nt] = __builtin_amdgcn_mfma_f32_16x16x32_bf16(afrag[0], b, acc[0][nt], 0,0,0);
                acc[1][nt] = __builtin_amdgcn_mfma_f32_16x16x32_bf16(afrag[1], b, acc[1][nt], 0,0,0);
            }
        }

        float* hbuf = u_hbuf;
        __syncthreads();
        for (int ww = 0; ww < 4; ++ww) {
            if (w == ww) {
                #pragma unroll
                for (int mt = 0; mt < 2; ++mt)
                #pragma unroll
                for (int nt = 0; nt < 8; ++nt)
                #pragma unroll
                for (int r = 0; r < 4; ++r) {
                    int e = mt*16 + quad*4 + r;
                    float* p = &hbuf[e*132 + nt*16 + l16];
                    if (ww == 0) *p = acc[mt][nt][r]; else *p += acc[mt][nt][r];
                }
            }
            __syncthreads();
        }
        {
            int e = t >> 3, p = t & 7;
            float s = 0.f, s2 = 0.f;
            #pragma unroll
            for (int q = 0; q < 16; ++q) {
                float x = hbuf[e*132 + p*16 + q];
                s += x; s2 += x*x;
            }
            part[e*8+p] = s; part2[e*8+p] = s2;
        }
        __syncthreads();
        if (t < 32) {
            float s = 0.f, s2 = 0.f;
            #pragma unroll
            for (int p = 0; p < 8; ++p) { s += part[t*8+p]; s2 += part2[t*8+p]; }
            float mu = s * (1.0f/128.0f);
            float var = s2 * (1.0f/128.0f) - mu*mu;
            smu[t] = mu; srs[t] = rsqrtf(var + 1e-5f);
        }
        __syncthreads();
        for (int it = t; it < 32*128; it += 256) {
            int e = it >> 7, f = it & 127;
            float x = hbuf[e*132 + f];
            out[OUT_E + (size_t)(id0 + e)*128 + f] = ge[f] * (x - smu[e]) * srs[e] + be[f];
        }
    }
}

extern "C" void kernel_launch(void* const* d_in, const int* in_sizes, int n_in,
                              void* d_out, int out_size, void* d_ws, size_t ws_size,
                              hipStream_t stream) {
    (void)in_sizes; (void)n_in; (void)out_size; (void)ws_size;
    const float* X     = (const float*)d_in[0];
    const float* mask  = (const float*)d_in[2];
    const float* amask = (const float*)d_in[3];
    const int*   ri    = (const int*)d_in[4];
    const int*   ch    = (const int*)d_in[6];
    const float* Wpos  = (const float*)d_in[7];
    const float* bpos  = (const float*)d_in[8];
    const float* We    = (const float*)d_in[9];
    const float* ge    = (const float*)d_in[10];
    const float* be    = (const float*)d_in[11];
    const float* Ws    = (const float*)d_in[12];
    const float* gs    = (const float*)d_in[13];
    const float* bs    = (const float*)d_in[14];

    float* out    = (float*)d_out;
    float* ws     = (float*)d_ws;
    float* coords = ws + WS_COORDS;
    float* Dnb    = ws + WS_DNB;
    int*   Eidx   = (int*)(ws + WS_EIDX);
    short* WpE    = (short*)(ws + WS_WPE);
    short* WpS    = (short*)(ws + WS_WPS);

    k_pre <<<dim3(900),  dim3(256), 0, stream>>>(X, mask, We, Ws, coords,
                                                 WpE, WpS, Dnb, Eidx, out);
    k_edge<<<dim3(3072), dim3(256), 0, stream>>>(coords, X, amask, WpE, WpS,
                                                 Dnb, Eidx, ri, ch, Wpos, bpos,
                                                 ge, be, gs, bs, out);
}